// Round 2
// baseline (181.211 us; speedup 1.0000x reference)
//
#include <hip/hip_runtime.h>

// Conv3d(8->32, k=3, VALID) + bias + HardSwish + GroupNorm(4) + mean pool.
// R7 = R6 (32x32x16 MFMA, tap-major/ci-minor K, B fragment = one ds_read_b128,
// conflict-free linear LDS) + bigger block tile 4z x 8y:
//  - halo overfetch 2.25x -> 1.875x, A-fragment reload traffic halved,
//    ws atomics halved (1152 blocks instead of 2304)
//  - LDS 48 KB/block, still 2 blocks/CU (96 KB < 160 KB)
// Per wave: 12 tiles x (14 ds_read_b128 + 28 MFMA). Bias folded into hi-chain
// accumulator init. hi/lo bf16 weight split kept (2 chains, dep distance 2).

#define IN 48
#define IN2 2304
#define IN3 110592
#define OUTD 46
#define RS 200            // row stride in dwords (48*4 used + pad for masked overread)
#define NROW 60           // 6 z-rows x 10 y-rows
#define WPK_OFF 1024      // dword offset of packed-weight table inside ws

typedef short v8s    __attribute__((ext_vector_type(8)));
typedef float f32x4  __attribute__((ext_vector_type(4)));
typedef float f32x16 __attribute__((ext_vector_type(16)));
typedef int   i32x4  __attribute__((ext_vector_type(4)));

__device__ __forceinline__ unsigned short f2bf(float f) {
    unsigned u = __builtin_bit_cast(unsigned, f);
    return (unsigned short)((u + 0x7fffu + ((u >> 16) & 1u)) >> 16);   // RNE
}
__device__ __forceinline__ float bf2f(unsigned short h) {
    unsigned u = ((unsigned)h) << 16;
    return __builtin_bit_cast(float, u);
}

// One-time: build lane-exact A fragments for 32x32x16.
// Layout: [hl 0..1][chunk c 0..13][lane 0..63][4 dw].
// Lane: co = lane&31, h = lane>>5. Chunk c covers taus {2c, 2c+1}; this lane
// holds tau = 2c+h, dword j = ci pair (2j lo, 2j+1 hi). tau>=27 -> zero.
__global__ __launch_bounds__(256) void pack_weights(
    const float* __restrict__ w, unsigned* __restrict__ wpk)
{
    int gid = blockIdx.x * 256 + threadIdx.x;
    if (gid >= 1792) return;
    int lane = gid & 63;
    int rest = gid >> 6;          // 0..27
    int c  = rest % 14;
    int hl = rest / 14;           // 0 = hi bf16, 1 = lo (residual)
    int co = lane & 31, h = lane >> 5;
    int tau = 2 * c + h;
    unsigned o[4];
    #pragma unroll
    for (int j = 0; j < 4; ++j) {
        if (tau >= 27) { o[j] = 0u; continue; }
        float w0 = w[(co * 8 + 2 * j) * 27 + tau];
        float w1 = w[(co * 8 + 2 * j + 1) * 27 + tau];
        unsigned short b0 = f2bf(w0), b1 = f2bf(w1);
        if (hl) {
            b0 = f2bf(w0 - bf2f(b0));
            b1 = f2bf(w1 - bf2f(b1));
        }
        o[j] = ((unsigned)b1 << 16) | b0;
    }
    *(i32x4*)(wpk + ((hl * 14 + c) * 64 + lane) * 4) =
        (i32x4){(int)o[0], (int)o[1], (int)o[2], (int)o[3]};
}

__global__ __launch_bounds__(256, 2) void conv_hs_mfma(
    const float* __restrict__ x, const unsigned* __restrict__ wpk,
    const float* __restrict__ bias, float* __restrict__ ws1, float* __restrict__ ws2)
{
    __shared__ unsigned xdw[NROW * RS];   // 48 KB: [row 60][e*4 + cipair] linear
    __shared__ float s1b[32], s2b[32];

    const int tid  = threadIdx.x;
    const int lane = tid & 63;
    const int wv   = tid >> 6;          // wave id = z offset within tile
    const int h    = lane >> 5;         // k-half: tau parity within chunk
    const int xi   = lane & 15;         // B col -> x offset
    const int yi   = (lane >> 4) & 1;   // B col -> y offset within ypair

    const int blk = blockIdx.x;
    const int b   = blk / 72;
    const int r0  = blk - b * 72;
    const int zb  = r0 / 6;
    const int yb  = r0 - zb * 6;
    const int z0  = zb * 4, y0 = yb * 8;
    const int z   = z0 + wv;

    if (tid < 32) { s1b[tid] = 0.f; s2b[tid] = 0.f; }

    // A fragments: 28 coalesced 16B loads from the precomputed table.
    i32x4 Ah[14], Al[14];
    #pragma unroll
    for (int c = 0; c < 14; ++c) {
        Ah[c] = *(const i32x4*)(wpk + ((0 * 14 + c) * 64 + lane) * 4);
        Al[c] = *(const i32x4*)(wpk + ((1 * 14 + c) * 64 + lane) * 4);
    }

    // C/D layout (32x32): col = lane&31, row(co) = (r&3) + 8*(r>>2) + 4*h
    float bias_r[16];
    #pragma unroll
    for (int r = 0; r < 16; ++r)
        bias_r[r] = bias[(r & 3) + 8 * (r >> 2) + 4 * h];

    // Per-lane chunk byte offsets into the LDS tile: tau = min(2c+h, 26).
    // (chunk 13 pads tau=27 -> clamp to a valid address; its A is zero.)
    int offv[14];
    #pragma unroll
    for (int c = 0; c < 14; ++c) {
        const int te = 2 * c;
        const int to = (2 * c + 1 > 26) ? 26 : 2 * c + 1;
        #define TOFF(t) ((((t) / 9) * 10 + (((t) % 9) / 3)) * (RS * 4) + ((t) % 3) * 16)
        offv[c] = h ? TOFF(to) : TOFF(te);
    }

    // ---- stage x tile, bf16 ci-pair packed, linear layout ----
    {
        const int q = tid & 3;
        const int e = tid >> 2;            // active e < 48
        if (e < 48) {
            const float* p0 = x + (b * 8 + 2 * q) * IN3 + e;
            const float* p1 = p0 + IN3;
            unsigned* dst = xdw + e * 4 + q;
            #pragma unroll
            for (int zr = 0; zr < 6; ++zr) {
                const int gz = min(z0 + zr, IN - 1);
                #pragma unroll
                for (int yr = 0; yr < 10; ++yr) {
                    const int gy = min(y0 + yr, IN - 1);
                    const int off = gz * IN2 + gy * IN;
                    float f0 = p0[off], f1 = p1[off];
                    dst[(zr * 10 + yr) * RS] = ((unsigned)f2bf(f1) << 16) | f2bf(f0);
                }
            }
        }
    }
    __syncthreads();

    float t1[16], t2[16];
    #pragma unroll
    for (int r = 0; r < 16; ++r) { t1[r] = 0.f; t2[r] = 0.f; }

    if (z < OUTD) {
        const int ypmax = min(4, (OUTD - y0) >> 1);
        for (int yp = 0; yp < ypmax; ++yp) {
            const char* bp = (const char*)xdw
                           + ((wv * 10 + 2 * yp + yi) * RS + xi * 4) * 4;
            #pragma unroll
            for (int xt = 0; xt < 3; ++xt) {
                const char* bx = bp + xt * 16 * 16;   // x0 = 16*xt
                f32x16 aH, aL;
                #pragma unroll
                for (int r = 0; r < 16; ++r) { aH[r] = bias_r[r]; aL[r] = 0.f; }
                #pragma unroll
                for (int c = 0; c < 14; ++c) {
                    i32x4 bd = *(const i32x4*)(bx + offv[c]);
                    v8s B = __builtin_bit_cast(v8s, bd);
                    aH = __builtin_amdgcn_mfma_f32_32x32x16_bf16(
                        __builtin_bit_cast(v8s, Ah[c]), B, aH, 0, 0, 0);
                    aL = __builtin_amdgcn_mfma_f32_32x32x16_bf16(
                        __builtin_bit_cast(v8s, Al[c]), B, aL, 0, 0, 0);
                }
                const bool xok = (xt * 16 + xi) < OUTD;
                #pragma unroll
                for (int r = 0; r < 16; ++r) {
                    float v = aH[r] + aL[r];             // bias already in aH
                    float u = fminf(fmaxf(v + 3.0f, 0.0f), 6.0f);
                    float hs = v * u * (1.0f / 6.0f);
                    float hm = xok ? hs : 0.f;
                    t1[r] += hm;
                    t2[r] = fmaf(hm, hm, t2[r]);
                }
            }
        }
    }

    // reduce over the 32 col-lanes within each k-half; channel set is per-(r,h)
    #pragma unroll
    for (int r = 0; r < 16; ++r) {
        #pragma unroll
        for (int k = 1; k < 32; k <<= 1) {
            t1[r] += __shfl_xor(t1[r], k, 64);
            t2[r] += __shfl_xor(t2[r], k, 64);
        }
    }
    if ((lane & 31) == 0) {
        #pragma unroll
        for (int r = 0; r < 16; ++r) {
            const int co = (r & 3) + 8 * (r >> 2) + 4 * h;
            atomicAdd(&s1b[co], t1[r]);
            atomicAdd(&s2b[co], t2[r]);
        }
    }
    __syncthreads();
    if (tid < 32)       atomicAdd(&ws1[b * 32 + tid], s1b[tid]);
    else if (tid < 64)  atomicAdd(&ws2[b * 32 + (tid - 32)], s2b[tid - 32]);
}

__global__ __launch_bounds__(512) void gn_finalize(
    const float* __restrict__ ws1, const float* __restrict__ ws2,
    const float* __restrict__ gnw, const float* __restrict__ gnb,
    float* __restrict__ out)
{
    int tid = threadIdx.x;
    int c = tid & 31;
    float s1 = ws1[tid], s2 = ws2[tid];
    float g1 = s1, g2 = s2;
    #pragma unroll
    for (int k = 1; k < 8; k <<= 1) {
        g1 += __shfl_xor(g1, k, 64);
        g2 += __shfl_xor(g2, k, 64);
    }
    const float Nsp  = 46.0f * 46.0f * 46.0f;
    const float invN = 1.0f / (8.0f * Nsp);
    float mean = g1 * invN;
    float var  = fmaxf(g2 * invN - mean * mean, 0.0f);
    float rstd = rsqrtf(var + 1e-5f);
    float mc   = s1 * (1.0f / Nsp);
    out[tid] = (mc - mean) * rstd * gnw[c] + gnb[c];
}

extern "C" void kernel_launch(void* const* d_in, const int* in_sizes, int n_in,
                              void* d_out, int out_size, void* d_ws, size_t ws_size,
                              hipStream_t stream) {
    const float* x    = (const float*)d_in[0];
    const float* w    = (const float*)d_in[1];
    const float* bias = (const float*)d_in[2];
    const float* gnw  = (const float*)d_in[3];
    const float* gnb  = (const float*)d_in[4];
    float* out = (float*)d_out;
    float* ws1 = (float*)d_ws;
    float* ws2 = ws1 + 512;
    unsigned* wpk = (unsigned*)d_ws + WPK_OFF;   // 7168 dwords

    hipMemsetAsync(d_ws, 0, 1024 * sizeof(float), stream);
    pack_weights<<<dim3(7), dim3(256), 0, stream>>>(w, wpk);
    conv_hs_mfma<<<dim3(16 * 12 * 6), dim3(256), 0, stream>>>(x, wpk, bias, ws1, ws2);
    gn_finalize<<<dim3(1), dim3(512), 0, stream>>>(ws1, ws2, gnw, gnb, out);
}